// Round 8
// baseline (177.629 us; speedup 1.0000x reference)
//
#include <hip/hip_runtime.h>
#include <hip/hip_bf16.h>
#include <math.h>

// Problem constants
#define C_DIM 256      // channels
#define SPAT 4096      // h*w = 64*64
#define HEADS_N 8
#define DHEAD 64
#define MEMTOK 4
#define TTOK 4100      // MEMTOK + SPAT
#define TTOKP 4224     // padded (33 tiles of 128)
#define HID 512        // HEADS_N * DHEAD
#define PSP 72         // epilogue LDS row pitch in bf16 elems (16B-aligned)

typedef __bf16 bf16x8 __attribute__((ext_vector_type(8)));
typedef unsigned short u16x8 __attribute__((ext_vector_type(8)));
typedef float f32x4 __attribute__((ext_vector_type(4)));

static __device__ inline unsigned short f2bf(float f) {  // RNE f32->bf16
    unsigned int u = __float_as_uint(f);
    u += 0x7fffu + ((u >> 16) & 1u);
    return (unsigned short)(u >> 16);
}

static __device__ inline bf16x8 ldb8(const void* p) {
    union { u16x8 u; bf16x8 b; } t;
    t.u = *(const u16x8*)p;
    return t.b;
}

static __device__ inline unsigned int pkbf(float a, float b) {  // packed bf16 pair
    union { __bf16 h[2]; unsigned int u; } t;
    t.h[0] = (__bf16)a; t.h[1] = (__bf16)b;
    return t.u;
}

// inverse of the per-32-token V key-permutation pi (pi: [b4b3b2]->[b2b4b3]).
static __device__ inline int pinv(int m) {
    return (m & 3) | (((m >> 4) & 1) << 2) | (((m >> 2) & 3) << 3);
}

// async global->LDS, 16B per lane (LDS dest = wave-uniform base + lane*16)
static __device__ inline void gload16(const void* g, void* l) {
    __builtin_amdgcn_global_load_lds(
        (const __attribute__((address_space(1))) unsigned int*)g,
        (__attribute__((address_space(3))) unsigned int*)l, 16, 0, 0);
}

#define DRAIN_BAR() do { \
    asm volatile("s_waitcnt vmcnt(0)\n\ts_barrier" ::: "memory"); \
    __builtin_amdgcn_sched_barrier(0); } while (0)

// ---------------------------------------------------------------------------
// Kernel 1: prep — all elementwise work, one launch, 1088 blocks.  (unchanged)
// ---------------------------------------------------------------------------
__global__ __launch_bounds__(256) void prep_kernel(
    const float* __restrict__ x, const float* __restrict__ gamma,
    const float* __restrict__ mem, const float* __restrict__ wq,
    const float* __restrict__ wo,
    unsigned short* __restrict__ xb, float* __restrict__ spb,
    unsigned short* __restrict__ wb, unsigned short* __restrict__ wob,
    unsigned short* __restrict__ kb, unsigned short* __restrict__ vtb) {
    __shared__ float XT[64][65];
    __shared__ float red[4][64];
    const int bid = blockIdx.x;
    const int t = threadIdx.x;
    if (bid < 256) {              // A: transpose-cast x
        int p0 = (bid & 63) * 64, c0 = (bid >> 6) * 64;
#pragma unroll
        for (int i = 0; i < 4; ++i) {
            int cl = i * 16 + (t >> 4), p4 = (t & 15) * 4;
            *(float4*)&XT[cl][p4] = *(const float4*)&x[(size_t)(c0 + cl) * SPAT + p0 + p4];
        }
        __syncthreads();
        int pl = t >> 2, cs = (t & 3) * 16;
        u16x8 a, b;
#pragma unroll
        for (int j = 0; j < 8; ++j) a[j] = f2bf(XT[cs + j][pl]);
#pragma unroll
        for (int j = 0; j < 8; ++j) b[j] = f2bf(XT[cs + 8 + j][pl]);
        *(u16x8*)&xb[(size_t)(p0 + pl) * C_DIM + c0 + cs] = a;
        *(u16x8*)&xb[(size_t)(p0 + pl) * C_DIM + c0 + cs + 8] = b;
    } else if (bid < 320) {       // B: norms
        int p = (bid - 256) * 64 + (t & 63);
        int g = t >> 6;
        float ss = 0.f;
        for (int c = g * 64; c < g * 64 + 64; ++c) {
            float v = x[(size_t)c * SPAT + p];
            ss += v * v;
        }
        red[g][t & 63] = ss;
        __syncthreads();
        if (g == 0) {
            int lp = t & 63;
            float tot = red[0][lp] + red[1][lp] + red[2][lp] + red[3][lp];
            spb[p] = rsqrtf(tot) * 16.0f;
        }
    } else if (bid < 512) {       // C: wb = bf16(wq * (gamma+1)), 8 elems/thread
        size_t idx = ((size_t)(bid - 320) * 256 + t) * 8;
        int c0 = (int)(idx & 255);
        float4 f0 = *(const float4*)&wq[idx];
        float4 f1 = *(const float4*)&wq[idx + 4];
        float4 g0 = *(const float4*)&gamma[c0];
        float4 g1 = *(const float4*)&gamma[c0 + 4];
        u16x8 pk;
        pk[0] = f2bf(f0.x * (g0.x + 1.f)); pk[1] = f2bf(f0.y * (g0.y + 1.f));
        pk[2] = f2bf(f0.z * (g0.z + 1.f)); pk[3] = f2bf(f0.w * (g0.w + 1.f));
        pk[4] = f2bf(f1.x * (g1.x + 1.f)); pk[5] = f2bf(f1.y * (g1.y + 1.f));
        pk[6] = f2bf(f1.z * (g1.z + 1.f)); pk[7] = f2bf(f1.w * (g1.w + 1.f));
        *(u16x8*)&wb[idx] = pk;
    } else if (bid < 576) {       // D: wob = bf16(wo)
        size_t idx = ((size_t)(bid - 512) * 256 + t) * 8;
        float4 f0 = *(const float4*)&wo[idx];
        float4 f1 = *(const float4*)&wo[idx + 4];
        u16x8 pk;
        pk[0] = f2bf(f0.x); pk[1] = f2bf(f0.y); pk[2] = f2bf(f0.z); pk[3] = f2bf(f0.w);
        pk[4] = f2bf(f1.x); pk[5] = f2bf(f1.y); pk[6] = f2bf(f1.z); pk[7] = f2bf(f1.w);
        *(u16x8*)&wob[idx] = pk;
    } else {                      // E: mem_kv + zero pads (131072 threads)
        int i = (bid - 576) * 256 + t;
        if (i < 4096) {
            int d = i & 63, m = (i >> 6) & 3, h = (i >> 8) & 7, s = (i >> 11) & 1;
            unsigned short val = f2bf(mem[i]);
            if (s == 0) kb[(size_t)h * TTOKP * 64 + m * 64 + d] = val;
            else        vtb[((size_t)h * 64 + d) * TTOKP + m] = val;
        } else {
            int z = i - 4096;              // 0..126975
            if (z < 63488) {               // kb pad rows 4100..4223 (124/head)
                int h = z / 7936, r = z % 7936;
                int row = TTOK + r / 64, d = r % 64;
                kb[(size_t)h * TTOKP * 64 + row * 64 + d] = 0;
            } else {                       // vtb pad cols 4100..4223
                z -= 63488;
                int h = z / 7936, r = z % 7936;
                int d = r / 124, tcol = TTOK + r % 124;
                vtb[((size_t)h * 64 + d) * TTOKP + tcol] = 0;
            }
        }
    }
}

// ---------------------------------------------------------------------------
// Kernel 2: QKV GEMM on MFMA (bf16 in, fp32 accum, bf16 out).  (unchanged)
// ---------------------------------------------------------------------------
__global__ __launch_bounds__(256) void qkv_mfma(const unsigned short* __restrict__ wb,
                                                const unsigned short* __restrict__ xb,
                                                const float* __restrict__ spb,
                                                unsigned short* __restrict__ qb,
                                                unsigned short* __restrict__ kb,
                                                unsigned short* __restrict__ vtb) {
    const int tile_p = blockIdx.x;      // 0..63
    const int tile_o = blockIdx.y;      // 0..23
    const int p0 = tile_p * 64, o0 = tile_o * 64;
    __shared__ unsigned short LB[4][64 * 128];  // W0,X0,W1,X1 chunk buffers

    const int t = threadIdx.x;
    const int w = t >> 6, lane = t & 63;
    const int col16 = lane & 15, quad = lane >> 4;
    const int c7 = col16 & 7;
    const char* gw = (const char*)(wb + (size_t)o0 * C_DIM);
    const char* gx = (const char*)(xb + (size_t)p0 * C_DIM);

    auto STG = [&](int ck, unsigned short* SWb, unsigned short* SXb) {
#pragma unroll
        for (int i = 0; i < 4; ++i) {
            int c4 = w * 4 + i;                       // 1KB chunk
            int row = c4 * 4 + (lane >> 4);           // 0..63
            int sl = (((lane & 15) ^ (row & 7)) << 4);
            size_t src = (size_t)row * 512 + ck * 256 + sl;
            gload16(gw + src, (char*)SWb + c4 * 1024);
            gload16(gx + src, (char*)SXb + c4 * 1024);
        }
    };

    f32x4 acc[4];
#pragma unroll
    for (int n = 0; n < 4; ++n) acc[n] = (f32x4){0.f, 0.f, 0.f, 0.f};
    const int arow = (w * 16 + col16) * 256;

    auto COMP = [&](const unsigned short* SWb, const unsigned short* SXb) {
#pragma unroll
        for (int kkl = 0; kkl < 4; ++kkl) {
            int ko = (((kkl * 4 + quad) ^ c7) << 4);
            bf16x8 a = ldb8((const char*)SWb + arow + ko);
#pragma unroll
            for (int n = 0; n < 4; ++n) {
                bf16x8 b = ldb8((const char*)SXb + (n * 16 + col16) * 256 + ko);
                acc[n] = __builtin_amdgcn_mfma_f32_16x16x32_bf16(a, b, acc[n], 0, 0, 0);
            }
        }
    };

    STG(0, LB[0], LB[1]);
    DRAIN_BAR();
    STG(1, LB[2], LB[3]);     // prefetch chunk 1 under chunk-0 compute
    COMP(LB[0], LB[1]);
    DRAIN_BAR();
    COMP(LB[2], LB[3]);

    // --- epilogue: apply sp[p] (and QSC for q), store ---
    float spv[4];
#pragma unroll
    for (int n = 0; n < 4; ++n) spv[n] = spb[p0 + n * 16 + col16];

    const int sec = tile_o >> 3, h = tile_o & 7;
    if (sec < 2) {
        const float qsc = (sec == 0) ? 0.125f * 1.4426950408889634f : 1.0f;
        unsigned short* Ot = &LB[0][0];               // reuse, pitch PSP
        __syncthreads();                              // all MFMA LDS reads done
#pragma unroll
        for (int n = 0; n < 4; ++n) {
            float s = qsc * spv[n];
            ushort4 v4 = {f2bf(acc[n][0] * s), f2bf(acc[n][1] * s),
                          f2bf(acc[n][2] * s), f2bf(acc[n][3] * s)};
            *(ushort4*)&Ot[(n * 16 + col16) * PSP + w * 16 + quad * 4] = v4;
        }
        __syncthreads();
        int prow = t >> 2, dseg = t & 3;
        u16x8 va = *(u16x8*)&Ot[prow * PSP + dseg * 16];
        u16x8 vb = *(u16x8*)&Ot[prow * PSP + dseg * 16 + 8];
        unsigned short* dst = (sec == 0)
            ? qb + (size_t)h * SPAT * 64 + (size_t)(p0 + prow) * 64
            : kb + (size_t)h * TTOKP * 64 + (size_t)(MEMTOK + p0 + prow) * 64;
        *(u16x8*)&dst[dseg * 16] = va;
        *(u16x8*)&dst[dseg * 16 + 8] = vb;
    } else {   // v: scatter to vtb[h][d][pinv-permuted token col]
        unsigned short* dst = vtb + (size_t)h * 64 * TTOKP;
#pragma unroll
        for (int n = 0; n < 4; ++n) {
            int tg = MEMTOK + p0 + n * 16 + col16;
            int c = (tg & ~31) | pinv(tg & 31);
            float s = spv[n];
#pragma unroll
            for (int r = 0; r < 4; ++r)
                dst[(size_t)(w * 16 + quad * 4 + r) * TTOKP + c] = f2bf(acc[n][r] * s);
        }
    }
}

// ---------------------------------------------------------------------------
// Kernel 3: flash attention, quadrant wave decomposition for 2x LDS-read reuse.
// Block = (head, 64 q-rows); grid 512; KVBLK=128, 33 steps (R5 geometry).
// Waves: qsub = w>>1 (q rows [qsub*32,+32), TWO A-frag sets), kh = w&1 (keys
// [kh*64,+64) of each 128-key tile).  Each K/V fragment read from LDS is used
// by BOTH q-subtiles -> 16 ds_read_b128 per 32 MFMAs per wave per step
// (R5 was 32: the LDS-read bound halves).  Per-wave online softmax on its
// key half (register-P PV, pi-permuted V); final fp32 intra-block merge of
// the two key halves via LDS (R7-verified logic).  Output obb[p][h*64+d].
// ---------------------------------------------------------------------------
__global__ __launch_bounds__(256) void attn_mfma(const unsigned short* __restrict__ qb,
                                                 const unsigned short* __restrict__ kb,
                                                 const unsigned short* __restrict__ vtb,
                                                 unsigned short* __restrict__ obb) {
    const int h  = blockIdx.x & 7;           // head-pinned XCD locality
    const int p0 = (blockIdx.x >> 3) * 64;

    __shared__ unsigned short LA[4][64 * 128];   // Ks0,Vs0,Ks1,Vs1 (16KB each)

    const int t = threadIdx.x;
    const int w = t >> 6;
    const int lane = t & 63;
    const int col16 = lane & 15;
    const int quad = lane >> 4;
    const int qsub = w >> 1;      // q sub-block (rows qsub*32 .. +31)
    const int kh = w & 1;         // key half (keys kh*64 .. +63 of each tile)
    const int cswz = col16 & 7;
    const int sw0 = ((quad ^ cswz) << 4);
    const int sw1 = (((quad + 4) ^ cswz) << 4);

    const unsigned short* qh = qb + (size_t)h * SPAT * 64;
    const char* khb = (const char*)(kb + (size_t)h * TTOKP * 64);
    const char* vhb = (const char*)(vtb + (size_t)h * 64 * TTOKP);

    // Q fragments: two q rows per lane (qq=0,1), rows p0+qsub*32+qq*16+col16
    bf16x8 aq0[2], aq1[2];
#pragma unroll
    for (int qq = 0; qq < 2; ++qq) {
        const unsigned short* qr = &qh[(size_t)(p0 + qsub * 32 + qq * 16 + col16) * 64];
        aq0[qq] = ldb8(qr + quad * 8);
        aq1[qq] = ldb8(qr + 32 + quad * 8);
    }

    float m_i[2] = {-1e30f, -1e30f}, l_i[2] = {0.f, 0.f};
    f32x4 Oa[2][4];
#pragma unroll
    for (int qq = 0; qq < 2; ++qq)
#pragma unroll
        for (int n = 0; n < 4; ++n) Oa[qq][n] = (f32x4){0.f, 0.f, 0.f, 0.f};

    // stage one 128-key tile (all 4 waves): K = 128 rows x 128B, V = 64 d x 256B
    auto STAGE = [&](int tb, unsigned short* Kd, unsigned short* Vd) {
#pragma unroll
        for (int i = 0; i < 4; ++i) {
            int ck = w * 4 + i;
            int krow = ck * 8 + (lane >> 3);                 // 0..127
            int kcol = (((lane & 7) ^ (lane >> 3)) << 4);    // krow&7 == lane>>3
            gload16(khb + (size_t)(tb * 128 + krow) * 128 + kcol, (char*)Kd + ck * 1024);
            int vrow = ck * 4 + (lane >> 4);                 // 0..63 (d)
            int vcol = (((lane & 15) ^ (vrow & 7)) << 4);
            gload16(vhb + (size_t)vrow * (TTOKP * 2) + (size_t)tb * 256 + vcol,
                    (char*)Vd + ck * 1024);
        }
    };

    auto STEP = [&](int tile, const unsigned short* Kc_, const unsigned short* Vc_,
                    unsigned short* Ksn, unsigned short* Vsn, bool stage, bool mask) {
        if (stage) STAGE(tile + 1, Ksn, Vsn);

        const char* Kc = (const char*)Kc_;
        const char* Vc = (const char*)Vc_;

        // S^T on this wave's key half; each K fragment feeds BOTH q-subtiles.
        // sv[qq][nn][r] = score(key kh*64+nn*16+quad*4+r, q-row qq)
        f32x4 sv[2][4];
#pragma unroll
        for (int nn = 0; nn < 4; ++nn) {
            int krow = kh * 64 + nn * 16 + col16;
            bf16x8 bk0 = ldb8(Kc + krow * 128 + sw0);
            bf16x8 bk1 = ldb8(Kc + krow * 128 + sw1);
#pragma unroll
            for (int qq = 0; qq < 2; ++qq) {
                f32x4 z = (f32x4){0.f, 0.f, 0.f, 0.f};
                z = __builtin_amdgcn_mfma_f32_16x16x32_bf16(bk0, aq0[qq], z, 0, 0, 0);
                sv[qq][nn] = __builtin_amdgcn_mfma_f32_16x16x32_bf16(bk1, aq1[qq], z, 0, 0, 0);
            }
        }

        if (mask) {   // tile 32: only tokens 4096..4099 (kh==0, nn==0, quad==0)
#pragma unroll
            for (int qq = 0; qq < 2; ++qq)
#pragma unroll
                for (int nn = 0; nn < 4; ++nn)
#pragma unroll
                    for (int r = 0; r < 4; ++r)
                        if ((kh | nn | quad) != 0) sv[qq][nn][r] = -1e30f;
        }

        // per-qq online softmax over this wave's 64 keys (15 fmax + 2 shfl each)
        float al[2];
#pragma unroll
        for (int qq = 0; qq < 2; ++qq) {
            float rm = fmaxf(
                fmaxf(fmaxf(sv[qq][0][0], sv[qq][0][1]), fmaxf(sv[qq][0][2], sv[qq][0][3])),
                fmaxf(fmaxf(sv[qq][1][0], sv[qq][1][1]), fmaxf(sv[qq][1][2], sv[qq][1][3])));
            rm = fmaxf(rm, fmaxf(
                fmaxf(fmaxf(sv[qq][2][0], sv[qq][2][1]), fmaxf(sv[qq][2][2], sv[qq][2][3])),
                fmaxf(fmaxf(sv[qq][3][0], sv[qq][3][1]), fmaxf(sv[qq][3][2], sv[qq][3][3]))));
            rm = fmaxf(rm, __shfl_xor(rm, 16, 64));
            rm = fmaxf(rm, __shfl_xor(rm, 32, 64));
            float mn = fmaxf(m_i[qq], rm);
            al[qq] = __builtin_amdgcn_exp2f(m_i[qq] - mn);
            m_i[qq] = mn;
            float sm[4];
#pragma unroll
            for (int nn = 0; nn < 4; ++nn) {
                float e0 = __builtin_amdgcn_exp2f(sv[qq][nn][0] - mn);
                float e1 = __builtin_amdgcn_exp2f(sv[qq][nn][1] - mn);
                float e2 = __builtin_amdgcn_exp2f(sv[qq][nn][2] - mn);
                float e3 = __builtin_amdgcn_exp2f(sv[qq][nn][3] - mn);
                sv[qq][nn][0] = e0; sv[qq][nn][1] = e1;
                sv[qq][nn][2] = e2; sv[qq][nn][3] = e3;
                sm[nn] = (e0 + e1) + (e2 + e3);
            }
            float rs = (sm[0] + sm[1]) + (sm[2] + sm[3]);
            rs += __shfl_xor(rs, 16, 64);
            rs += __shfl_xor(rs, 32, 64);
            l_i[qq] = l_i[qq] * al[qq] + rs;
#pragma unroll
            for (int n = 0; n < 4; ++n) {
                Oa[qq][n][0] *= al[qq]; Oa[qq][n][1] *= al[qq];
                Oa[qq][n][2] *= al[qq]; Oa[qq][n][3] *= al[qq];
            }
        }

        // PV: each V fragment feeds BOTH q-subtiles (pi-permuted V keys)
#pragma unroll
        for (int ff = 0; ff < 2; ++ff) {
            int F = kh * 2 + ff;                         // 32-key group 0..3
            int vo = (((F * 4 + quad) ^ cswz) << 4);
            bf16x8 bv[4];
#pragma unroll
            for (int n = 0; n < 4; ++n)
                bv[n] = ldb8(Vc + (n * 16 + col16) * 256 + vo);
#pragma unroll
            for (int qq = 0; qq < 2; ++qq) {
                union { unsigned int u[4]; bf16x8 v; } pu;
                pu.u[0] = pkbf(sv[qq][2 * ff][0], sv[qq][2 * ff][1]);
                pu.u[1] = pkbf(sv[qq][2 * ff][2], sv[qq][2 * ff][3]);
                pu.u[2] = pkbf(sv[qq][2 * ff + 1][0], sv[qq][2 * ff + 1][1]);
                pu.u[3] = pkbf(sv[qq][2 * ff + 1][2], sv[qq][2 * ff + 1][3]);
#pragma unroll
                for (int n = 0; n < 4; ++n)
                    Oa[qq][n] = __builtin_amdgcn_mfma_f32_16x16x32_bf16(bv[n], pu.v,
                                                                        Oa[qq][n], 0, 0, 0);
            }
        }

        if (!mask) DRAIN_BAR();
    };

    STAGE(0, LA[0], LA[1]);
    DRAIN_BAR();
    for (int b = 0; b < 32; b += 2) {
        STEP(b,     LA[0], LA[1], LA[2], LA[3], true, false);
        STEP(b + 1, LA[2], LA[3], LA[0], LA[1], true, false);
    }
    STEP(32, LA[0], LA[1], LA[2], LA[3], false, true);   // no stage, masked

    // ---- intra-block merge of the two key halves (fp32) + store obb ----
    __syncthreads();                                     // all LDS reads done
    float* MB = (float*)&LA[0][0];                       // [64 q][68] f32 (17408B)
    float2* ML = (float2*)((char*)&LA[0][0] + 64 * 68 * 4);   // 64 float2
    __bf16* TR = (__bf16*)&LA[2][0];                     // kh=0 transpose region

    if (kh == 1) {                // publish partial (m,l,O) for this wave's rows
#pragma unroll
        for (int qq = 0; qq < 2; ++qq) {
            float* row = MB + (qsub * 32 + qq * 16 + col16) * 68;
#pragma unroll
            for (int n = 0; n < 4; ++n)
#pragma unroll
                for (int r = 0; r < 4; ++r)
                    row[n * 16 + quad * 4 + r] = Oa[qq][n][r];
            if (quad == 0)
                ML[qsub * 32 + qq * 16 + col16] = make_float2(m_i[qq], l_i[qq]);
        }
    }
    __syncthreads();
    if (kh == 0) {
#pragma unroll
        for (int qq = 0; qq < 2; ++qq) {
            float2 o = ML[qsub * 32 + qq * 16 + col16];
            float M = fmaxf(m_i[qq], o.x);
            float a0 = __builtin_amdgcn_exp2f(m_i[qq] - M);
            float a1 = __builtin_amdgcn_exp2f(o.x - M);
            float inv = 1.0f / (a0 * l_i[qq] + a1 * o.y);
            const float* row = MB + (qsub * 32 + qq * 16 + col16) * 68;
            __bf16* ot = TR + (size_t)(qsub * 32 + qq * 16) * PSP;
#pragma unroll
            for (int n = 0; n < 4; ++n) {
                float v0 = (a0 * Oa[qq][n][0] + a1 * row[n * 16 + quad * 4 + 0]) * inv;
                float v1 = (a0 * Oa[qq][n][1] + a1 * row[n * 16 + quad * 4 + 1]) * inv;
                float v2 = (a0 * Oa[qq][n][2] + a1 * row[n * 16 + quad * 4 + 2]) * inv;
                float v3 = (a0 * Oa[qq][n][3] + a1 * row[n * 16 + quad * 4 + 3]) * inv;
                *(unsigned int*)&ot[col16 * PSP + n * 16 + quad * 4]     = pkbf(v0, v1);
                *(unsigned int*)&ot[col16 * PSP + n * 16 + quad * 4 + 2] = pkbf(v2, v3);
            }
        }
        // transpose-read + coalesced store (per-wave region, same-wave idiom)
        int q2 = lane >> 2, dseg = (lane & 3) * 16;
#pragma unroll
        for (int qq = 0; qq < 2; ++qq) {
            const unsigned short* otr =
                (const unsigned short*)(TR + (size_t)(qsub * 32 + qq * 16) * PSP);
            u16x8 o0v = *(const u16x8*)&otr[q2 * PSP + dseg];
            u16x8 o1v = *(const u16x8*)&otr[q2 * PSP + dseg + 8];
            unsigned short* dst = obb +
                (size_t)(p0 + qsub * 32 + qq * 16 + q2) * HID + h * DHEAD + dseg;
            *(u16x8*)&dst[0] = o0v;
            *(u16x8*)&dst[8] = o1v;
        }
    }
}

// ---------------------------------------------------------------------------
// Kernel 4: out projection on MFMA (bf16 in, fp32 accum, fp32 out).
// (R5 version, verbatim — verified.)
// ---------------------------------------------------------------------------
__global__ __launch_bounds__(256) void out_mfma(const unsigned short* __restrict__ wob,
                                                const unsigned short* __restrict__ obb,
                                                float* __restrict__ out) {
    const int p0 = blockIdx.x * 64;
    const int o0 = blockIdx.y * 64;
    __shared__ unsigned short LB[4][64 * 128];   // W0,O0,W1,O1 chunk buffers

    const int t = threadIdx.x;
    const int w = t >> 6, lane = t & 63;
    const int col16 = lane & 15, quad = lane >> 4;
    const int c7 = col16 & 7;
    const char* gw = (const char*)(wob + (size_t)o0 * HID);
    const char* go = (const char*)(obb + (size_t)p0 * HID);

    auto STG = [&](int ck, unsigned short* SWb, unsigned short* SOb) {
#pragma unroll
        for (int i = 0; i < 4; ++i) {
            int c4 = w * 4 + i;
            int row = c4 * 4 + (lane >> 4);
            int sl = (((lane & 15) ^ (row & 7)) << 4);
            size_t src = (size_t)row * 1024 + ck * 256 + sl;
            gload16(gw + src, (char*)SWb + c4 * 1024);
            gload16(go + src, (char*)SOb + c4 * 1024);
        }
    };

    f32x4 acc[4];
#pragma unroll
    for (int n = 0; n < 4; ++n) acc[n] = (f32x4){0.f, 0.f, 0.f, 0.f};
    const int arow = (w * 16 + col16) * 256;

    auto COMP = [&](const unsigned short* SWb, const unsigned short* SOb) {
#pragma unroll
        for (int kkl = 0; kkl < 4; ++kkl) {
            int ko = (((kkl * 4 + quad) ^ c7) << 4);
            bf16x8 a = ldb8((const char*)SWb + arow + ko);
#pragma unroll
            for (int n = 0; n < 4; ++n) {
                bf16x8 b = ldb8((const char*)SOb + (n * 16 + col16) * 256 + ko);
                acc[n] = __builtin_amdgcn_mfma_f32_16x16x32_bf16(a, b, acc[n], 0, 0, 0);
            }
        }
    };

    STG(0, LB[0], LB[1]);
    DRAIN_BAR();
    STG(1, LB[2], LB[3]);  COMP(LB[0], LB[1]);  DRAIN_BAR();
    STG(2, LB[0], LB[1]);  COMP(LB[2], LB[3]);  DRAIN_BAR();
    STG(3, LB[2], LB[3]);  COMP(LB[0], LB[1]);  DRAIN_BAR();
    COMP(LB[2], LB[3]);

    // epilogue: D[o][p] -> per-wave LDS transpose -> coalesced float4 stores
    __syncthreads();
    float* otw = (float*)&LB[0][0] + (size_t)w * (16 * 68);
#pragma unroll
    for (int n = 0; n < 4; ++n)
#pragma unroll
        for (int r = 0; r < 4; ++r)
            otw[(quad * 4 + r) * 68 + n * 16 + col16] = acc[n][r];
    int r2 = lane >> 2, csg = (lane & 3) * 16;
#pragma unroll
    for (int j = 0; j < 4; ++j) {
        float4 v = *(const float4*)&otw[r2 * 68 + csg + j * 4];
        *(float4*)&out[(size_t)(o0 + w * 16 + r2) * SPAT + p0 + csg + j * 4] = v;
    }
}

// ---------------------------------------------------------------------------
// Launch
// ---------------------------------------------------------------------------
extern "C" void kernel_launch(void* const* d_in, const int* in_sizes, int n_in,
                              void* d_out, int out_size, void* d_ws, size_t ws_size,
                              hipStream_t stream) {
    const float* x      = (const float*)d_in[0];
    const float* gamma  = (const float*)d_in[1];
    const float* mem_kv = (const float*)d_in[2];
    const float* w_qkv  = (const float*)d_in[3];
    const float* w_out  = (const float*)d_in[4];
    float* out = (float*)d_out;

    // workspace (bf16 unless noted): xb | wb | wob | qb | kb | vtb | obb | spb(f32)
    unsigned short* xb  = (unsigned short*)d_ws;                 // 4096*256
    unsigned short* wb  = xb + (size_t)SPAT * C_DIM;             // 1536*256
    unsigned short* wob = wb + (size_t)3 * HID * C_DIM;          // 256*512
    unsigned short* qb  = wob + (size_t)C_DIM * HID;             // 8*4096*64
    unsigned short* kb  = qb + (size_t)HEADS_N * SPAT * DHEAD;   // 8*4224*64
    unsigned short* vtb = kb + (size_t)HEADS_N * TTOKP * DHEAD;  // 8*64*4224
    unsigned short* obb = vtb + (size_t)HEADS_N * DHEAD * TTOKP; // 4096*512
    float* spb = (float*)(obb + (size_t)SPAT * HID);             // 4096

    prep_kernel<<<dim3(1088), 256, 0, stream>>>(x, gamma, mem_kv, w_qkv, w_out,
                                                xb, spb, wb, wob, kb, vtb);
    qkv_mfma<<<dim3(64, 24), 256, 0, stream>>>(wb, xb, spb, qb, kb, vtb);
    attn_mfma<<<dim3(512), 256, 0, stream>>>(qb, kb, vtb, obb);
    out_mfma<<<dim3(64, 4), 256, 0, stream>>>(wob, obb, out);
}

// Round 10
// 155.426 us; speedup vs baseline: 1.1429x; 1.1429x over previous
//
#include <hip/hip_runtime.h>
#include <hip/hip_bf16.h>
#include <math.h>

// Problem constants
#define C_DIM 256      // channels
#define SPAT 4096      // h*w = 64*64
#define HEADS_N 8
#define DHEAD 64
#define MEMTOK 4
#define TTOK 4100      // MEMTOK + SPAT
#define TTOKP 4224     // padded (33 tiles of 128)
#define HID 512        // HEADS_N * DHEAD
#define PSP 72         // epilogue LDS row pitch in bf16 elems (16B-aligned)

typedef __bf16 bf16x8 __attribute__((ext_vector_type(8)));
typedef unsigned short u16x8 __attribute__((ext_vector_type(8)));
typedef float f32x4 __attribute__((ext_vector_type(4)));

static __device__ inline unsigned short f2bf(float f) {  // RNE f32->bf16
    unsigned int u = __float_as_uint(f);
    u += 0x7fffu + ((u >> 16) & 1u);
    return (unsigned short)(u >> 16);
}

static __device__ inline bf16x8 ldb8(const void* p) {
    union { u16x8 u; bf16x8 b; } t;
    t.u = *(const u16x8*)p;
    return t.b;
}

static __device__ inline unsigned int pkbf(float a, float b) {  // packed bf16 pair
    union { __bf16 h[2]; unsigned int u; } t;
    t.h[0] = (__bf16)a; t.h[1] = (__bf16)b;
    return t.u;
}

// inverse of the per-32-token V key-permutation pi (pi: [b4b3b2]->[b2b4b3]).
static __device__ inline int pinv(int m) {
    return (m & 3) | (((m >> 4) & 1) << 2) | (((m >> 2) & 3) << 3);
}

// async global->LDS, 16B per lane (LDS dest = wave-uniform base + lane*16)
static __device__ inline void gload16(const void* g, void* l) {
    __builtin_amdgcn_global_load_lds(
        (const __attribute__((address_space(1))) unsigned int*)g,
        (__attribute__((address_space(3))) unsigned int*)l, 16, 0, 0);
}

#define DRAIN_BAR() do { \
    asm volatile("s_waitcnt vmcnt(0)\n\ts_barrier" ::: "memory"); \
    __builtin_amdgcn_sched_barrier(0); } while (0)

// ---------------------------------------------------------------------------
// Kernel 1: prep — all elementwise work, one launch, 1088 blocks.  (unchanged)
// ---------------------------------------------------------------------------
__global__ __launch_bounds__(256) void prep_kernel(
    const float* __restrict__ x, const float* __restrict__ gamma,
    const float* __restrict__ mem, const float* __restrict__ wq,
    const float* __restrict__ wo,
    unsigned short* __restrict__ xb, float* __restrict__ spb,
    unsigned short* __restrict__ wb, unsigned short* __restrict__ wob,
    unsigned short* __restrict__ kb, unsigned short* __restrict__ vtb) {
    __shared__ float XT[64][65];
    __shared__ float red[4][64];
    const int bid = blockIdx.x;
    const int t = threadIdx.x;
    if (bid < 256) {              // A: transpose-cast x
        int p0 = (bid & 63) * 64, c0 = (bid >> 6) * 64;
#pragma unroll
        for (int i = 0; i < 4; ++i) {
            int cl = i * 16 + (t >> 4), p4 = (t & 15) * 4;
            *(float4*)&XT[cl][p4] = *(const float4*)&x[(size_t)(c0 + cl) * SPAT + p0 + p4];
        }
        __syncthreads();
        int pl = t >> 2, cs = (t & 3) * 16;
        u16x8 a, b;
#pragma unroll
        for (int j = 0; j < 8; ++j) a[j] = f2bf(XT[cs + j][pl]);
#pragma unroll
        for (int j = 0; j < 8; ++j) b[j] = f2bf(XT[cs + 8 + j][pl]);
        *(u16x8*)&xb[(size_t)(p0 + pl) * C_DIM + c0 + cs] = a;
        *(u16x8*)&xb[(size_t)(p0 + pl) * C_DIM + c0 + cs + 8] = b;
    } else if (bid < 320) {       // B: norms
        int p = (bid - 256) * 64 + (t & 63);
        int g = t >> 6;
        float ss = 0.f;
        for (int c = g * 64; c < g * 64 + 64; ++c) {
            float v = x[(size_t)c * SPAT + p];
            ss += v * v;
        }
        red[g][t & 63] = ss;
        __syncthreads();
        if (g == 0) {
            int lp = t & 63;
            float tot = red[0][lp] + red[1][lp] + red[2][lp] + red[3][lp];
            spb[p] = rsqrtf(tot) * 16.0f;
        }
    } else if (bid < 512) {       // C: wb = bf16(wq * (gamma+1)), 8 elems/thread
        size_t idx = ((size_t)(bid - 320) * 256 + t) * 8;
        int c0 = (int)(idx & 255);
        float4 f0 = *(const float4*)&wq[idx];
        float4 f1 = *(const float4*)&wq[idx + 4];
        float4 g0 = *(const float4*)&gamma[c0];
        float4 g1 = *(const float4*)&gamma[c0 + 4];
        u16x8 pk;
        pk[0] = f2bf(f0.x * (g0.x + 1.f)); pk[1] = f2bf(f0.y * (g0.y + 1.f));
        pk[2] = f2bf(f0.z * (g0.z + 1.f)); pk[3] = f2bf(f0.w * (g0.w + 1.f));
        pk[4] = f2bf(f1.x * (g1.x + 1.f)); pk[5] = f2bf(f1.y * (g1.y + 1.f));
        pk[6] = f2bf(f1.z * (g1.z + 1.f)); pk[7] = f2bf(f1.w * (g1.w + 1.f));
        *(u16x8*)&wb[idx] = pk;
    } else if (bid < 576) {       // D: wob = bf16(wo)
        size_t idx = ((size_t)(bid - 512) * 256 + t) * 8;
        float4 f0 = *(const float4*)&wo[idx];
        float4 f1 = *(const float4*)&wo[idx + 4];
        u16x8 pk;
        pk[0] = f2bf(f0.x); pk[1] = f2bf(f0.y); pk[2] = f2bf(f0.z); pk[3] = f2bf(f0.w);
        pk[4] = f2bf(f1.x); pk[5] = f2bf(f1.y); pk[6] = f2bf(f1.z); pk[7] = f2bf(f1.w);
        *(u16x8*)&wob[idx] = pk;
    } else {                      // E: mem_kv + zero pads (131072 threads)
        int i = (bid - 576) * 256 + t;
        if (i < 4096) {
            int d = i & 63, m = (i >> 6) & 3, h = (i >> 8) & 7, s = (i >> 11) & 1;
            unsigned short val = f2bf(mem[i]);
            if (s == 0) kb[(size_t)h * TTOKP * 64 + m * 64 + d] = val;
            else        vtb[((size_t)h * 64 + d) * TTOKP + m] = val;
        } else {
            int z = i - 4096;              // 0..126975
            if (z < 63488) {               // kb pad rows 4100..4223 (124/head)
                int h = z / 7936, r = z % 7936;
                int row = TTOK + r / 64, d = r % 64;
                kb[(size_t)h * TTOKP * 64 + row * 64 + d] = 0;
            } else {                       // vtb pad cols 4100..4223
                z -= 63488;
                int h = z / 7936, r = z % 7936;
                int d = r / 124, tcol = TTOK + r % 124;
                vtb[((size_t)h * 64 + d) * TTOKP + tcol] = 0;
            }
        }
    }
}

// ---------------------------------------------------------------------------
// Kernel 2: QKV GEMM on MFMA (bf16 in, fp32 accum, bf16 out).  (unchanged)
// ---------------------------------------------------------------------------
__global__ __launch_bounds__(256) void qkv_mfma(const unsigned short* __restrict__ wb,
                                                const unsigned short* __restrict__ xb,
                                                const float* __restrict__ spb,
                                                unsigned short* __restrict__ qb,
                                                unsigned short* __restrict__ kb,
                                                unsigned short* __restrict__ vtb) {
    const int tile_p = blockIdx.x;      // 0..63
    const int tile_o = blockIdx.y;      // 0..23
    const int p0 = tile_p * 64, o0 = tile_o * 64;
    __shared__ unsigned short LB[4][64 * 128];  // W0,X0,W1,X1 chunk buffers

    const int t = threadIdx.x;
    const int w = t >> 6, lane = t & 63;
    const int col16 = lane & 15, quad = lane >> 4;
    const int c7 = col16 & 7;
    const char* gw = (const char*)(wb + (size_t)o0 * C_DIM);
    const char* gx = (const char*)(xb + (size_t)p0 * C_DIM);

    auto STG = [&](int ck, unsigned short* SWb, unsigned short* SXb) {
#pragma unroll
        for (int i = 0; i < 4; ++i) {
            int c4 = w * 4 + i;                       // 1KB chunk
            int row = c4 * 4 + (lane >> 4);           // 0..63
            int sl = (((lane & 15) ^ (row & 7)) << 4);
            size_t src = (size_t)row * 512 + ck * 256 + sl;
            gload16(gw + src, (char*)SWb + c4 * 1024);
            gload16(gx + src, (char*)SXb + c4 * 1024);
        }
    };

    f32x4 acc[4];
#pragma unroll
    for (int n = 0; n < 4; ++n) acc[n] = (f32x4){0.f, 0.f, 0.f, 0.f};
    const int arow = (w * 16 + col16) * 256;

    auto COMP = [&](const unsigned short* SWb, const unsigned short* SXb) {
#pragma unroll
        for (int kkl = 0; kkl < 4; ++kkl) {
            int ko = (((kkl * 4 + quad) ^ c7) << 4);
            bf16x8 a = ldb8((const char*)SWb + arow + ko);
#pragma unroll
            for (int n = 0; n < 4; ++n) {
                bf16x8 b = ldb8((const char*)SXb + (n * 16 + col16) * 256 + ko);
                acc[n] = __builtin_amdgcn_mfma_f32_16x16x32_bf16(a, b, acc[n], 0, 0, 0);
            }
        }
    };

    STG(0, LB[0], LB[1]);
    DRAIN_BAR();
    STG(1, LB[2], LB[3]);     // prefetch chunk 1 under chunk-0 compute
    COMP(LB[0], LB[1]);
    DRAIN_BAR();
    COMP(LB[2], LB[3]);

    // --- epilogue: apply sp[p] (and QSC for q), store ---
    float spv[4];
#pragma unroll
    for (int n = 0; n < 4; ++n) spv[n] = spb[p0 + n * 16 + col16];

    const int sec = tile_o >> 3, h = tile_o & 7;
    if (sec < 2) {
        const float qsc = (sec == 0) ? 0.125f * 1.4426950408889634f : 1.0f;
        unsigned short* Ot = &LB[0][0];               // reuse, pitch PSP
        __syncthreads();                              // all MFMA LDS reads done
#pragma unroll
        for (int n = 0; n < 4; ++n) {
            float s = qsc * spv[n];
            ushort4 v4 = {f2bf(acc[n][0] * s), f2bf(acc[n][1] * s),
                          f2bf(acc[n][2] * s), f2bf(acc[n][3] * s)};
            *(ushort4*)&Ot[(n * 16 + col16) * PSP + w * 16 + quad * 4] = v4;
        }
        __syncthreads();
        int prow = t >> 2, dseg = t & 3;
        u16x8 va = *(u16x8*)&Ot[prow * PSP + dseg * 16];
        u16x8 vb = *(u16x8*)&Ot[prow * PSP + dseg * 16 + 8];
        unsigned short* dst = (sec == 0)
            ? qb + (size_t)h * SPAT * 64 + (size_t)(p0 + prow) * 64
            : kb + (size_t)h * TTOKP * 64 + (size_t)(MEMTOK + p0 + prow) * 64;
        *(u16x8*)&dst[dseg * 16] = va;
        *(u16x8*)&dst[dseg * 16 + 8] = vb;
    } else {   // v: scatter to vtb[h][d][pinv-permuted token col]
        unsigned short* dst = vtb + (size_t)h * 64 * TTOKP;
#pragma unroll
        for (int n = 0; n < 4; ++n) {
            int tg = MEMTOK + p0 + n * 16 + col16;
            int c = (tg & ~31) | pinv(tg & 31);
            float s = spv[n];
#pragma unroll
            for (int r = 0; r < 4; ++r)
                dst[(size_t)(w * 16 + quad * 4 + r) * TTOKP + c] = f2bf(acc[n][r] * s);
        }
    }
}

// ---------------------------------------------------------------------------
// Kernel 3: flash attention — R5-exact (verified at 77us, absmax 0.00195).
// Block = (head, 64 q-rows); grid 512; KVBLK=128, 33 steps; 16 q-rows/wave,
// all 128 keys per wave; register-P PV (pi-permuted V); double-buffered
// global_load_lds with fused vmcnt(0)+s_barrier per step.
// Output obb[p][h*64+d] bf16 via per-wave LDS transpose.
// ---------------------------------------------------------------------------
__global__ __launch_bounds__(256) void attn_mfma(const unsigned short* __restrict__ qb,
                                                 const unsigned short* __restrict__ kb,
                                                 const unsigned short* __restrict__ vtb,
                                                 unsigned short* __restrict__ obb) {
    const int h  = blockIdx.x & 7;           // head-pinned XCD locality
    const int p0 = (blockIdx.x >> 3) * 64;

    __shared__ unsigned short LA[4][64 * 128];   // Ks0,Vs0,Ks1,Vs1 (16KB each)

    const int t = threadIdx.x;
    const int w = t >> 6;
    const int lane = t & 63;
    const int col16 = lane & 15;
    const int quad = lane >> 4;
    const int cswz = col16 & 7;
    const int sw0 = ((quad ^ cswz) << 4);
    const int sw1 = (((quad + 4) ^ cswz) << 4);

    const unsigned short* qh = qb + (size_t)h * SPAT * 64;
    const char* khb = (const char*)(kb + (size_t)h * TTOKP * 64);
    const char* vhb = (const char*)(vtb + (size_t)h * 64 * TTOKP);

    bf16x8 aq0 = ldb8(&qh[(size_t)(p0 + w * 16 + col16) * 64 + quad * 8]);
    bf16x8 aq1 = ldb8(&qh[(size_t)(p0 + w * 16 + col16) * 64 + 32 + quad * 8]);

    float m_i = -1e30f, l_i = 0.f;
    f32x4 Oa[4];
#pragma unroll
    for (int n = 0; n < 4; ++n) Oa[n] = (f32x4){0.f, 0.f, 0.f, 0.f};

    // stage one 128-key tile: K = 128 rows x 128B, V = 64 d x 256B
    auto STAGE = [&](int tb, unsigned short* Kd, unsigned short* Vd) {
#pragma unroll
        for (int i = 0; i < 4; ++i) {
            int ck = w * 4 + i;
            int krow = ck * 8 + (lane >> 3);                 // 0..127
            int kcol = (((lane & 7) ^ (lane >> 3)) << 4);    // krow&7 == lane>>3
            gload16(khb + (size_t)(tb * 128 + krow) * 128 + kcol, (char*)Kd + ck * 1024);
            int vrow = ck * 4 + (lane >> 4);                 // 0..63 (d)
            int vcol = (((lane & 15) ^ (vrow & 7)) << 4);
            gload16(vhb + (size_t)vrow * (TTOKP * 2) + (size_t)tb * 256 + vcol,
                    (char*)Vd + ck * 1024);
        }
    };

    auto STEP = [&](int tile, const unsigned short* Kc_, const unsigned short* Vc_,
                    unsigned short* Ksn, unsigned short* Vsn, bool stage, bool mask) {
        if (stage) STAGE(tile + 1, Ksn, Vsn);

        const char* Kc = (const char*)Kc_;
        const char* Vc = (const char*)Vc_;

        // S^T: sv[n][r] = score for key n*16+quad*4+r, q = col16 (per wave)
        f32x4 sv[8];
#pragma unroll
        for (int n = 0; n < 8; ++n) {
            sv[n] = (f32x4){0.f, 0.f, 0.f, 0.f};
            bf16x8 bk0 = ldb8(Kc + (n * 16 + col16) * 128 + sw0);
            bf16x8 bk1 = ldb8(Kc + (n * 16 + col16) * 128 + sw1);
            sv[n] = __builtin_amdgcn_mfma_f32_16x16x32_bf16(bk0, aq0, sv[n], 0, 0, 0);
            sv[n] = __builtin_amdgcn_mfma_f32_16x16x32_bf16(bk1, aq1, sv[n], 0, 0, 0);
        }

        if (mask) {   // final tile: only tokens 4096..4099 valid (n==0,quad==0)
#pragma unroll
            for (int n = 0; n < 8; ++n)
#pragma unroll
                for (int r = 0; r < 4; ++r)
                    if ((n | quad) != 0) sv[n][r] = -1e30f;
        }

        // row max: 31 local fmax (tree) + 2 shfl
        float mx[8];
#pragma unroll
        for (int n = 0; n < 8; ++n)
            mx[n] = fmaxf(fmaxf(sv[n][0], sv[n][1]), fmaxf(sv[n][2], sv[n][3]));
        float rm = fmaxf(fmaxf(fmaxf(mx[0], mx[1]), fmaxf(mx[2], mx[3])),
                         fmaxf(fmaxf(mx[4], mx[5]), fmaxf(mx[6], mx[7])));
        rm = fmaxf(rm, __shfl_xor(rm, 16, 64));
        rm = fmaxf(rm, __shfl_xor(rm, 32, 64));

        float mn = fmaxf(m_i, rm);
        float al = __builtin_amdgcn_exp2f(m_i - mn);
        m_i = mn;

        float sm[8];
#pragma unroll
        for (int n = 0; n < 8; ++n) {
            float e0 = __builtin_amdgcn_exp2f(sv[n][0] - mn);
            float e1 = __builtin_amdgcn_exp2f(sv[n][1] - mn);
            float e2 = __builtin_amdgcn_exp2f(sv[n][2] - mn);
            float e3 = __builtin_amdgcn_exp2f(sv[n][3] - mn);
            sv[n][0] = e0; sv[n][1] = e1; sv[n][2] = e2; sv[n][3] = e3;
            sm[n] = (e0 + e1) + (e2 + e3);
        }
        float rs = ((sm[0] + sm[1]) + (sm[2] + sm[3])) +
                   ((sm[4] + sm[5]) + (sm[6] + sm[7]));
        rs += __shfl_xor(rs, 16, 64);
        rs += __shfl_xor(rs, 32, 64);
        l_i = l_i * al + rs;

#pragma unroll
        for (int n = 0; n < 4; ++n) {
            Oa[n][0] *= al; Oa[n][1] *= al; Oa[n][2] *= al; Oa[n][3] *= al;
        }

        // PV: P fragments straight from registers (pi-permuted V keys)
#pragma unroll
        for (int f = 0; f < 4; ++f) {
            union { unsigned int u[4]; bf16x8 v; } pu;
            pu.u[0] = pkbf(sv[2 * f][0], sv[2 * f][1]);
            pu.u[1] = pkbf(sv[2 * f][2], sv[2 * f][3]);
            pu.u[2] = pkbf(sv[2 * f + 1][0], sv[2 * f + 1][1]);
            pu.u[3] = pkbf(sv[2 * f + 1][2], sv[2 * f + 1][3]);
            int vo = (((f * 4 + quad) ^ cswz) << 4);
#pragma unroll
            for (int n = 0; n < 4; ++n) {
                bf16x8 bv = ldb8(Vc + (n * 16 + col16) * 256 + vo);
                Oa[n] = __builtin_amdgcn_mfma_f32_16x16x32_bf16(bv, pu.v, Oa[n], 0, 0, 0);
            }
        }

        if (!mask) DRAIN_BAR();
    };

    STAGE(0, LA[0], LA[1]);
    DRAIN_BAR();
    for (int b = 0; b < 32; b += 2) {
        STEP(b,     LA[0], LA[1], LA[2], LA[3], true, false);
        STEP(b + 1, LA[2], LA[3], LA[0], LA[1], true, false);
    }
    STEP(32, LA[0], LA[1], LA[2], LA[3], false, true);

    // epilogue: O^T/l -> bf16, per-wave LDS transpose -> obb[p][h*64+d]
    __syncthreads();                                  // all waves done reading LA
    float inv = 1.0f / l_i;
    __bf16* ot = (__bf16*)&LA[0][0] + (size_t)w * 16 * PSP;
#pragma unroll
    for (int n = 0; n < 4; ++n) {
        *(unsigned int*)&ot[col16 * PSP + n * 16 + quad * 4] =
            pkbf(Oa[n][0] * inv, Oa[n][1] * inv);
        *(unsigned int*)&ot[col16 * PSP + n * 16 + quad * 4 + 2] =
            pkbf(Oa[n][2] * inv, Oa[n][3] * inv);
    }
    int q2 = lane >> 2, dseg = (lane & 3) * 16;
    const unsigned short* otr = (const unsigned short*)ot;
    u16x8 o0v = *(const u16x8*)&otr[q2 * PSP + dseg];
    u16x8 o1v = *(const u16x8*)&otr[q2 * PSP + dseg + 8];
    unsigned short* dst = obb + (size_t)(p0 + w * 16 + q2) * HID + h * DHEAD + dseg;
    *(u16x8*)&dst[0] = o0v;
    *(u16x8*)&dst[8] = o1v;
}

// ---------------------------------------------------------------------------
// Kernel 4: out projection on MFMA (bf16 in, fp32 accum, fp32 out).
// out[o][p] = sum_hd wob[o][hd] * obb[p][hd].  Now 64 o x 32 p tiles,
// grid (128,4) = 512 blocks (2/CU, was 1/CU) — halves the per-block serial
// K-chain.  Same verified stage/compute/swizzle pattern with O-rows halved.
// LDS 48KB: SW 2x16KB (W, 64 rows), SO 2x8KB (O, 32 rows).
// ---------------------------------------------------------------------------
__global__ __launch_bounds__(256) void out_mfma(const unsigned short* __restrict__ wob,
                                                const unsigned short* __restrict__ obb,
                                                float* __restrict__ out) {
    const int p0 = blockIdx.x * 32;   // 128 p-tiles
    const int o0 = blockIdx.y * 64;   // 4 o-tiles
    __shared__ unsigned short SW0[64 * 128], SW1[64 * 128];   // 16KB each
    __shared__ unsigned short SO0[32 * 128], SO1[32 * 128];   // 8KB each

    const int t = threadIdx.x;
    const int w = t >> 6, lane = t & 63;
    const int col16 = lane & 15, quad = lane >> 4;
    const int c7 = col16 & 7;
    const char* gw = (const char*)(wob + (size_t)o0 * HID);
    const char* go = (const char*)(obb + (size_t)p0 * HID);

    auto STG = [&](int ck, unsigned short* SWb, unsigned short* SOb) {
#pragma unroll
        for (int i = 0; i < 4; ++i) {       // W: 16 chunks of 1KB, 4/wave
            int c4 = w * 4 + i;
            int row = c4 * 4 + (lane >> 4);                  // 0..63
            int sl = (((lane & 15) ^ (row & 7)) << 4);
            gload16(gw + (size_t)row * 1024 + ck * 256 + sl, (char*)SWb + c4 * 1024);
        }
#pragma unroll
        for (int i = 0; i < 2; ++i) {       // O: 8 chunks of 1KB, 2/wave
            int c2 = w * 2 + i;
            int row = c2 * 4 + (lane >> 4);                  // 0..31
            int sl = (((lane & 15) ^ (row & 7)) << 4);
            gload16(go + (size_t)row * 1024 + ck * 256 + sl, (char*)SOb + c2 * 1024);
        }
    };

    f32x4 acc[2];
#pragma unroll
    for (int n = 0; n < 2; ++n) acc[n] = (f32x4){0.f, 0.f, 0.f, 0.f};
    const int arow = (w * 16 + col16) * 256;

    auto COMP = [&](const unsigned short* SWb, const unsigned short* SOb) {
#pragma unroll
        for (int kkl = 0; kkl < 4; ++kkl) {
            int ko = (((kkl * 4 + quad) ^ c7) << 4);
            bf16x8 a = ldb8((const char*)SWb + arow + ko);
#pragma unroll
            for (int n = 0; n < 2; ++n) {
                bf16x8 b = ldb8((const char*)SOb + (n * 16 + col16) * 256 + ko);
                acc[n] = __builtin_amdgcn_mfma_f32_16x16x32_bf16(a, b, acc[n], 0, 0, 0);
            }
        }
    };

    STG(0, SW0, SO0);
    DRAIN_BAR();
    STG(1, SW1, SO1);  COMP(SW0, SO0);  DRAIN_BAR();
    STG(2, SW0, SO0);  COMP(SW1, SO1);  DRAIN_BAR();
    STG(3, SW1, SO1);  COMP(SW0, SO0);  DRAIN_BAR();
    COMP(SW1, SO1);

    // epilogue: D[o = w*16+quad*4+r][p = n*16+col16] -> per-wave LDS
    // transpose (pitch 36 f32, region in SW0 — not read by last COMP) ->
    // coalesced float4 stores.
    __syncthreads();
    float* otw = (float*)&SW0[0] + (size_t)w * (16 * 36);
#pragma unroll
    for (int n = 0; n < 2; ++n)
#pragma unroll
        for (int r = 0; r < 4; ++r)
            otw[(quad * 4 + r) * 36 + n * 16 + col16] = acc[n][r];
    int r2 = lane >> 2, csg = (lane & 3) * 8;
#pragma unroll
    for (int j = 0; j < 2; ++j) {
        float4 v = *(const float4*)&otw[r2 * 36 + csg + j * 4];
        *(float4*)&out[(size_t)(o0 + w * 16 + r2) * SPAT + p0 + csg + j * 4] = v;
    }
}

// ---------------------------------------------------------------------------
// Launch
// ---------------------------------------------------------------------------
extern "C" void kernel_launch(void* const* d_in, const int* in_sizes, int n_in,
                              void* d_out, int out_size, void* d_ws, size_t ws_size,
                              hipStream_t stream) {
    const float* x      = (const float*)d_in[0];
    const float* gamma  = (const float*)d_in[1];
    const float* mem_kv = (const float*)d_in[2];
    const float* w_qkv  = (const float*)d_in[3];
    const float* w_out  = (const float*)d_in[4];
    float* out = (float*)d_out;

    // workspace (bf16 unless noted): xb | wb | wob | qb | kb | vtb | obb | spb(f32)
    unsigned short* xb  = (unsigned short*)d_ws;                 // 4096*256
    unsigned short* wb  = xb + (size_t)SPAT * C_DIM;             // 1536*256
    unsigned short* wob = wb + (size_t)3 * HID * C_DIM;          // 256*512
    unsigned short* qb  = wob + (size_t)C_DIM * HID;             // 8*4096*64
    unsigned short* kb  = qb + (size_t)HEADS_N * SPAT * DHEAD;   // 8*4224*64
    unsigned short* vtb = kb + (size_t)HEADS_N * TTOKP * DHEAD;  // 8*64*4224
    unsigned short* obb = vtb + (size_t)HEADS_N * DHEAD * TTOKP; // 4096*512
    float* spb = (float*)(obb + (size_t)SPAT * HID);             // 4096

    prep_kernel<<<dim3(1088), 256, 0, stream>>>(x, gamma, mem_kv, w_qkv, w_out,
                                                xb, spb, wb, wob, kb, vtb);
    qkv_mfma<<<dim3(64, 24), 256, 0, stream>>>(wb, xb, spb, qb, kb, vtb);
    attn_mfma<<<dim3(512), 256, 0, stream>>>(qb, kb, vtb, obb);
    out_mfma<<<dim3(128, 4), 256, 0, stream>>>(wob, obb, out);
}

// Round 13
// 154.729 us; speedup vs baseline: 1.1480x; 1.0045x over previous
//
#include <hip/hip_runtime.h>
#include <hip/hip_bf16.h>
#include <math.h>

// Problem constants
#define C_DIM 256      // channels
#define SPAT 4096      // h*w = 64*64
#define HEADS_N 8
#define DHEAD 64
#define MEMTOK 4
#define TTOK 4100      // MEMTOK + SPAT
#define TTOKP 4224     // padded (33 tiles of 128)
#define HID 512        // HEADS_N * DHEAD
#define PSP 72         // epilogue LDS row pitch in bf16 elems (16B-aligned)

typedef __bf16 bf16x8 __attribute__((ext_vector_type(8)));
typedef unsigned short u16x8 __attribute__((ext_vector_type(8)));
typedef float f32x4 __attribute__((ext_vector_type(4)));

static __device__ inline unsigned short f2bf(float f) {  // RNE f32->bf16
    unsigned int u = __float_as_uint(f);
    u += 0x7fffu + ((u >> 16) & 1u);
    return (unsigned short)(u >> 16);
}

static __device__ inline bf16x8 ldb8(const void* p) {
    union { u16x8 u; bf16x8 b; } t;
    t.u = *(const u16x8*)p;
    return t.b;
}

static __device__ inline unsigned int pkbf(float a, float b) {  // packed bf16 pair
    union { __bf16 h[2]; unsigned int u; } t;
    t.h[0] = (__bf16)a; t.h[1] = (__bf16)b;
    return t.u;
}

// inverse of the per-32-token V key-permutation pi (pi: [b4b3b2]->[b2b4b3]).
static __device__ inline int pinv(int m) {
    return (m & 3) | (((m >> 4) & 1) << 2) | (((m >> 2) & 3) << 3);
}

// async global->LDS, 16B per lane (LDS dest = wave-uniform base + lane*16)
static __device__ inline void gload16(const void* g, void* l) {
    __builtin_amdgcn_global_load_lds(
        (const __attribute__((address_space(1))) unsigned int*)g,
        (__attribute__((address_space(3))) unsigned int*)l, 16, 0, 0);
}

#define DRAIN_BAR() do { \
    asm volatile("s_waitcnt vmcnt(0)\n\ts_barrier" ::: "memory"); \
    __builtin_amdgcn_sched_barrier(0); } while (0)

// ---------------------------------------------------------------------------
// Kernel 1: prep — all elementwise work, one launch, 1088 blocks.
// ---------------------------------------------------------------------------
__global__ __launch_bounds__(256) void prep_kernel(
    const float* __restrict__ x, const float* __restrict__ gamma,
    const float* __restrict__ mem, const float* __restrict__ wq,
    const float* __restrict__ wo,
    unsigned short* __restrict__ xb, float* __restrict__ spb,
    unsigned short* __restrict__ wb, unsigned short* __restrict__ wob,
    unsigned short* __restrict__ kb, unsigned short* __restrict__ vtb) {
    __shared__ float XT[64][65];
    __shared__ float red[4][64];
    const int bid = blockIdx.x;
    const int t = threadIdx.x;
    if (bid < 256) {              // A: transpose-cast x
        int p0 = (bid & 63) * 64, c0 = (bid >> 6) * 64;
#pragma unroll
        for (int i = 0; i < 4; ++i) {
            int cl = i * 16 + (t >> 4), p4 = (t & 15) * 4;
            *(float4*)&XT[cl][p4] = *(const float4*)&x[(size_t)(c0 + cl) * SPAT + p0 + p4];
        }
        __syncthreads();
        int pl = t >> 2, cs = (t & 3) * 16;
        u16x8 a, b;
#pragma unroll
        for (int j = 0; j < 8; ++j) a[j] = f2bf(XT[cs + j][pl]);
#pragma unroll
        for (int j = 0; j < 8; ++j) b[j] = f2bf(XT[cs + 8 + j][pl]);
        *(u16x8*)&xb[(size_t)(p0 + pl) * C_DIM + c0 + cs] = a;
        *(u16x8*)&xb[(size_t)(p0 + pl) * C_DIM + c0 + cs + 8] = b;
    } else if (bid < 320) {       // B: norms
        int p = (bid - 256) * 64 + (t & 63);
        int g = t >> 6;
        float ss = 0.f;
        for (int c = g * 64; c < g * 64 + 64; ++c) {
            float v = x[(size_t)c * SPAT + p];
            ss += v * v;
        }
        red[g][t & 63] = ss;
        __syncthreads();
        if (g == 0) {
            int lp = t & 63;
            float tot = red[0][lp] + red[1][lp] + red[2][lp] + red[3][lp];
            spb[p] = rsqrtf(tot) * 16.0f;
        }
    } else if (bid < 512) {       // C: wb = bf16(wq * (gamma+1)), 8 elems/thread
        size_t idx = ((size_t)(bid - 320) * 256 + t) * 8;
        int c0 = (int)(idx & 255);
        float4 f0 = *(const float4*)&wq[idx];
        float4 f1 = *(const float4*)&wq[idx + 4];
        float4 g0 = *(const float4*)&gamma[c0];
        float4 g1 = *(const float4*)&gamma[c0 + 4];
        u16x8 pk;
        pk[0] = f2bf(f0.x * (g0.x + 1.f)); pk[1] = f2bf(f0.y * (g0.y + 1.f));
        pk[2] = f2bf(f0.z * (g0.z + 1.f)); pk[3] = f2bf(f0.w * (g0.w + 1.f));
        pk[4] = f2bf(f1.x * (g1.x + 1.f)); pk[5] = f2bf(f1.y * (g1.y + 1.f));
        pk[6] = f2bf(f1.z * (g1.z + 1.f)); pk[7] = f2bf(f1.w * (g1.w + 1.f));
        *(u16x8*)&wb[idx] = pk;
    } else if (bid < 576) {       // D: wob = bf16(wo)
        size_t idx = ((size_t)(bid - 512) * 256 + t) * 8;
        float4 f0 = *(const float4*)&wo[idx];
        float4 f1 = *(const float4*)&wo[idx + 4];
        u16x8 pk;
        pk[0] = f2bf(f0.x); pk[1] = f2bf(f0.y); pk[2] = f2bf(f0.z); pk[3] = f2bf(f0.w);
        pk[4] = f2bf(f1.x); pk[5] = f2bf(f1.y); pk[6] = f2bf(f1.z); pk[7] = f2bf(f1.w);
        *(u16x8*)&wob[idx] = pk;
    } else {                      // E: mem_kv + zero pads (131072 threads)
        int i = (bid - 576) * 256 + t;
        if (i < 4096) {
            int d = i & 63, m = (i >> 6) & 3, h = (i >> 8) & 7, s = (i >> 11) & 1;
            unsigned short val = f2bf(mem[i]);
            if (s == 0) kb[(size_t)h * TTOKP * 64 + m * 64 + d] = val;
            else        vtb[((size_t)h * 64 + d) * TTOKP + m] = val;
        } else {
            int z = i - 4096;              // 0..126975
            if (z < 63488) {               // kb pad rows 4100..4223 (124/head)
                int h = z / 7936, r = z % 7936;
                int row = TTOK + r / 64, d = r % 64;
                kb[(size_t)h * TTOKP * 64 + row * 64 + d] = 0;
            } else {                       // vtb pad cols 4100..4223
                z -= 63488;
                int h = z / 7936, r = z % 7936;
                int d = r / 124, tcol = TTOK + r % 124;
                vtb[((size_t)h * 64 + d) * TTOKP + tcol] = 0;
            }
        }
    }
}

// ---------------------------------------------------------------------------
// Kernel 2: QKV GEMM on MFMA (bf16 in, fp32 accum, bf16 out).
// ---------------------------------------------------------------------------
__global__ __launch_bounds__(256) void qkv_mfma(const unsigned short* __restrict__ wb,
                                                const unsigned short* __restrict__ xb,
                                                const float* __restrict__ spb,
                                                unsigned short* __restrict__ qb,
                                                unsigned short* __restrict__ kb,
                                                unsigned short* __restrict__ vtb) {
    const int tile_p = blockIdx.x;      // 0..63
    const int tile_o = blockIdx.y;      // 0..23
    const int p0 = tile_p * 64, o0 = tile_o * 64;
    __shared__ unsigned short LB[4][64 * 128];  // W0,X0,W1,X1 chunk buffers

    const int t = threadIdx.x;
    const int w = t >> 6, lane = t & 63;
    const int col16 = lane & 15, quad = lane >> 4;
    const int c7 = col16 & 7;
    const char* gw = (const char*)(wb + (size_t)o0 * C_DIM);
    const char* gx = (const char*)(xb + (size_t)p0 * C_DIM);

    auto STG = [&](int ck, unsigned short* SWb, unsigned short* SXb) {
#pragma unroll
        for (int i = 0; i < 4; ++i) {
            int c4 = w * 4 + i;                       // 1KB chunk
            int row = c4 * 4 + (lane >> 4);           // 0..63
            int sl = (((lane & 15) ^ (row & 7)) << 4);
            size_t src = (size_t)row * 512 + ck * 256 + sl;
            gload16(gw + src, (char*)SWb + c4 * 1024);
            gload16(gx + src, (char*)SXb + c4 * 1024);
        }
    };

    f32x4 acc[4];
#pragma unroll
    for (int n = 0; n < 4; ++n) acc[n] = (f32x4){0.f, 0.f, 0.f, 0.f};
    const int arow = (w * 16 + col16) * 256;

    auto COMP = [&](const unsigned short* SWb, const unsigned short* SXb) {
#pragma unroll
        for (int kkl = 0; kkl < 4; ++kkl) {
            int ko = (((kkl * 4 + quad) ^ c7) << 4);
            bf16x8 a = ldb8((const char*)SWb + arow + ko);
#pragma unroll
            for (int n = 0; n < 4; ++n) {
                bf16x8 b = ldb8((const char*)SXb + (n * 16 + col16) * 256 + ko);
                acc[n] = __builtin_amdgcn_mfma_f32_16x16x32_bf16(a, b, acc[n], 0, 0, 0);
            }
        }
    };

    STG(0, LB[0], LB[1]);
    DRAIN_BAR();
    STG(1, LB[2], LB[3]);     // prefetch chunk 1 under chunk-0 compute
    COMP(LB[0], LB[1]);
    DRAIN_BAR();
    COMP(LB[2], LB[3]);

    // --- epilogue: apply sp[p] (and QSC for q), store ---
    float spv[4];
#pragma unroll
    for (int n = 0; n < 4; ++n) spv[n] = spb[p0 + n * 16 + col16];

    const int sec = tile_o >> 3, h = tile_o & 7;
    if (sec < 2) {
        const float qsc = (sec == 0) ? 0.125f * 1.4426950408889634f : 1.0f;
        unsigned short* Ot = &LB[0][0];               // reuse, pitch PSP
        __syncthreads();                              // all MFMA LDS reads done
#pragma unroll
        for (int n = 0; n < 4; ++n) {
            float s = qsc * spv[n];
            ushort4 v4 = {f2bf(acc[n][0] * s), f2bf(acc[n][1] * s),
                          f2bf(acc[n][2] * s), f2bf(acc[n][3] * s)};
            *(ushort4*)&Ot[(n * 16 + col16) * PSP + w * 16 + quad * 4] = v4;
        }
        __syncthreads();
        int prow = t >> 2, dseg = t & 3;
        u16x8 va = *(u16x8*)&Ot[prow * PSP + dseg * 16];
        u16x8 vb = *(u16x8*)&Ot[prow * PSP + dseg * 16 + 8];
        unsigned short* dst = (sec == 0)
            ? qb + (size_t)h * SPAT * 64 + (size_t)(p0 + prow) * 64
            : kb + (size_t)h * TTOKP * 64 + (size_t)(MEMTOK + p0 + prow) * 64;
        *(u16x8*)&dst[dseg * 16] = va;
        *(u16x8*)&dst[dseg * 16 + 8] = vb;
    } else {   // v: scatter to vtb[h][d][pinv-permuted token col]
        unsigned short* dst = vtb + (size_t)h * 64 * TTOKP;
#pragma unroll
        for (int n = 0; n < 4; ++n) {
            int tg = MEMTOK + p0 + n * 16 + col16;
            int c = (tg & ~31) | pinv(tg & 31);
            float s = spv[n];
#pragma unroll
            for (int r = 0; r < 4; ++r)
                dst[(size_t)(w * 16 + quad * 4 + r) * TTOKP + c] = f2bf(acc[n][r] * s);
        }
    }
}

// ---------------------------------------------------------------------------
// Kernel 3: flash attention — R5-exact (verified at 77us, absmax 0.00195).
// Block = (head, 64 q-rows); grid 512; KVBLK=128, 33 steps; 16 q-rows/wave,
// all 128 keys per wave; register-P PV (pi-permuted V); double-buffered
// global_load_lds with fused vmcnt(0)+s_barrier per step.
// Output obb[p][h*64+d] bf16 via per-wave LDS transpose.
// ---------------------------------------------------------------------------
__global__ __launch_bounds__(256) void attn_mfma(const unsigned short* __restrict__ qb,
                                                 const unsigned short* __restrict__ kb,
                                                 const unsigned short* __restrict__ vtb,
                                                 unsigned short* __restrict__ obb) {
    const int h  = blockIdx.x & 7;           // head-pinned XCD locality
    const int p0 = (blockIdx.x >> 3) * 64;

    __shared__ unsigned short LA[4][64 * 128];   // Ks0,Vs0,Ks1,Vs1 (16KB each)

    const int t = threadIdx.x;
    const int w = t >> 6;
    const int lane = t & 63;
    const int col16 = lane & 15;
    const int quad = lane >> 4;
    const int cswz = col16 & 7;
    const int sw0 = ((quad ^ cswz) << 4);
    const int sw1 = (((quad + 4) ^ cswz) << 4);

    const unsigned short* qh = qb + (size_t)h * SPAT * 64;
    const char* khb = (const char*)(kb + (size_t)h * TTOKP * 64);
    const char* vhb = (const char*)(vtb + (size_t)h * 64 * TTOKP);

    bf16x8 aq0 = ldb8(&qh[(size_t)(p0 + w * 16 + col16) * 64 + quad * 8]);
    bf16x8 aq1 = ldb8(&qh[(size_t)(p0 + w * 16 + col16) * 64 + 32 + quad * 8]);

    float m_i = -1e30f, l_i = 0.f;
    f32x4 Oa[4];
#pragma unroll
    for (int n = 0; n < 4; ++n) Oa[n] = (f32x4){0.f, 0.f, 0.f, 0.f};

    // stage one 128-key tile: K = 128 rows x 128B, V = 64 d x 256B
    auto STAGE = [&](int tb, unsigned short* Kd, unsigned short* Vd) {
#pragma unroll
        for (int i = 0; i < 4; ++i) {
            int ck = w * 4 + i;
            int krow = ck * 8 + (lane >> 3);                 // 0..127
            int kcol = (((lane & 7) ^ (lane >> 3)) << 4);    // krow&7 == lane>>3
            gload16(khb + (size_t)(tb * 128 + krow) * 128 + kcol, (char*)Kd + ck * 1024);
            int vrow = ck * 4 + (lane >> 4);                 // 0..63 (d)
            int vcol = (((lane & 15) ^ (vrow & 7)) << 4);
            gload16(vhb + (size_t)vrow * (TTOKP * 2) + (size_t)tb * 256 + vcol,
                    (char*)Vd + ck * 1024);
        }
    };

    auto STEP = [&](int tile, const unsigned short* Kc_, const unsigned short* Vc_,
                    unsigned short* Ksn, unsigned short* Vsn, bool stage, bool mask) {
        if (stage) STAGE(tile + 1, Ksn, Vsn);

        const char* Kc = (const char*)Kc_;
        const char* Vc = (const char*)Vc_;

        // S^T: sv[n][r] = score for key n*16+quad*4+r, q = col16 (per wave)
        f32x4 sv[8];
#pragma unroll
        for (int n = 0; n < 8; ++n) {
            sv[n] = (f32x4){0.f, 0.f, 0.f, 0.f};
            bf16x8 bk0 = ldb8(Kc + (n * 16 + col16) * 128 + sw0);
            bf16x8 bk1 = ldb8(Kc + (n * 16 + col16) * 128 + sw1);
            sv[n] = __builtin_amdgcn_mfma_f32_16x16x32_bf16(bk0, aq0, sv[n], 0, 0, 0);
            sv[n] = __builtin_amdgcn_mfma_f32_16x16x32_bf16(bk1, aq1, sv[n], 0, 0, 0);
        }

        if (mask) {   // final tile: only tokens 4096..4099 valid (n==0,quad==0)
#pragma unroll
            for (int n = 0; n < 8; ++n)
#pragma unroll
                for (int r = 0; r < 4; ++r)
                    if ((n | quad) != 0) sv[n][r] = -1e30f;
        }

        // row max: 31 local fmax (tree) + 2 shfl
        float mx[8];
#pragma unroll
        for (int n = 0; n < 8; ++n)
            mx[n] = fmaxf(fmaxf(sv[n][0], sv[n][1]), fmaxf(sv[n][2], sv[n][3]));
        float rm = fmaxf(fmaxf(fmaxf(mx[0], mx[1]), fmaxf(mx[2], mx[3])),
                         fmaxf(fmaxf(mx[4], mx[5]), fmaxf(mx[6], mx[7])));
        rm = fmaxf(rm, __shfl_xor(rm, 16, 64));
        rm = fmaxf(rm, __shfl_xor(rm, 32, 64));

        float mn = fmaxf(m_i, rm);
        float al = __builtin_amdgcn_exp2f(m_i - mn);
        m_i = mn;

        float sm[8];
#pragma unroll
        for (int n = 0; n < 8; ++n) {
            float e0 = __builtin_amdgcn_exp2f(sv[n][0] - mn);
            float e1 = __builtin_amdgcn_exp2f(sv[n][1] - mn);
            float e2 = __builtin_amdgcn_exp2f(sv[n][2] - mn);
            float e3 = __builtin_amdgcn_exp2f(sv[n][3] - mn);
            sv[n][0] = e0; sv[n][1] = e1; sv[n][2] = e2; sv[n][3] = e3;
            sm[n] = (e0 + e1) + (e2 + e3);
        }
        float rs = ((sm[0] + sm[1]) + (sm[2] + sm[3])) +
                   ((sm[4] + sm[5]) + (sm[6] + sm[7]));
        rs += __shfl_xor(rs, 16, 64);
        rs += __shfl_xor(rs, 32, 64);
        l_i = l_i * al + rs;

#pragma unroll
        for (int n = 0; n < 4; ++n) {
            Oa[n][0] *= al; Oa[n][1] *= al; Oa[n][2] *= al; Oa[n][3] *= al;
        }

        // PV: P fragments straight from registers (pi-permuted V keys)
#pragma unroll
        for (int f = 0; f < 4; ++f) {
            union { unsigned int u[4]; bf16x8 v; } pu;
            pu.u[0] = pkbf(sv[2 * f][0], sv[2 * f][1]);
            pu.u[1] = pkbf(sv[2 * f][2], sv[2 * f][3]);
            pu.u[2] = pkbf(sv[2 * f + 1][0], sv[2 * f + 1][1]);
            pu.u[3] = pkbf(sv[2 * f + 1][2], sv[2 * f + 1][3]);
            int vo = (((f * 4 + quad) ^ cswz) << 4);
#pragma unroll
            for (int n = 0; n < 4; ++n) {
                bf16x8 bv = ldb8(Vc + (n * 16 + col16) * 256 + vo);
                Oa[n] = __builtin_amdgcn_mfma_f32_16x16x32_bf16(bv, pu.v, Oa[n], 0, 0, 0);
            }
        }

        if (!mask) DRAIN_BAR();
    };

    STAGE(0, LA[0], LA[1]);
    DRAIN_BAR();
    for (int b = 0; b < 32; b += 2) {
        STEP(b,     LA[0], LA[1], LA[2], LA[3], true, false);
        STEP(b + 1, LA[2], LA[3], LA[0], LA[1], true, false);
    }
    STEP(32, LA[0], LA[1], LA[2], LA[3], false, true);

    // epilogue: O^T/l -> bf16, per-wave LDS transpose -> obb[p][h*64+d]
    __syncthreads();                                  // all waves done reading LA
    float inv = 1.0f / l_i;
    __bf16* ot = (__bf16*)&LA[0][0] + (size_t)w * 16 * PSP;
#pragma unroll
    for (int n = 0; n < 4; ++n) {
        *(unsigned int*)&ot[col16 * PSP + n * 16 + quad * 4] =
            pkbf(Oa[n][0] * inv, Oa[n][1] * inv);
        *(unsigned int*)&ot[col16 * PSP + n * 16 + quad * 4 + 2] =
            pkbf(Oa[n][2] * inv, Oa[n][3] * inv);
    }
    int q2 = lane >> 2, dseg = (lane & 3) * 16;
    const unsigned short* otr = (const unsigned short*)ot;
    u16x8 o0v = *(const u16x8*)&otr[q2 * PSP + dseg];
    u16x8 o1v = *(const u16x8*)&otr[q2 * PSP + dseg + 8];
    unsigned short* dst = obb + (size_t)(p0 + w * 16 + q2) * HID + h * DHEAD + dseg;
    *(u16x8*)&dst[0] = o0v;
    *(u16x8*)&dst[8] = o1v;
}

// ---------------------------------------------------------------------------
// Kernel 4: out projection on MFMA (bf16 in, fp32 accum, fp32 out).
// 64 o x 32 p tiles, grid (128,4) = 512 blocks (2/CU).
// ---------------------------------------------------------------------------
__global__ __launch_bounds__(256) void out_mfma(const unsigned short* __restrict__ wob,
                                                const unsigned short* __restrict__ obb,
                                                float* __restrict__ out) {
    const int p0 = blockIdx.x * 32;   // 128 p-tiles
    const int o0 = blockIdx.y * 64;   // 4 o-tiles
    __shared__ unsigned short SW0[64 * 128], SW1[64 * 128];   // 16KB each
    __shared__ unsigned short SO0[32 * 128], SO1[32 * 128];   // 8KB each

    const int t = threadIdx.x;
    const int w = t >> 6, lane = t & 63;
    const int col16 = lane & 15, quad = lane >> 4;
    const int c7 = col16 & 7;
    const char* gw = (const char*)(wob + (size_t)o0 * HID);
    const char* go = (const char*)(obb + (size_t)p0 * HID);

    auto STG = [&](int ck, unsigned short* SWb, unsigned short* SOb) {
#pragma unroll
        for (int i = 0; i < 4; ++i) {       // W: 16 chunks of 1KB, 4/wave
            int c4 = w * 4 + i;
            int row = c4 * 4 + (lane >> 4);                  // 0..63
            int sl = (((lane & 15) ^ (row & 7)) << 4);
            gload16(gw + (size_t)row * 1024 + ck * 256 + sl, (char*)SWb + c4 * 1024);
        }
#pragma unroll
        for (int i = 0; i < 2; ++i) {       // O: 8 chunks of 1KB, 2/wave
            int c2 = w * 2 + i;
            int row = c2 * 4 + (lane >> 4);                  // 0..31
            int sl = (((lane & 15) ^ (row & 7)) << 4);
            gload16(go + (size_t)row * 1024 + ck * 256 + sl, (char*)SOb + c2 * 1024);
        }
    };

    f32x4 acc[2];
#pragma unroll
    for (int n = 0; n < 2; ++n) acc[n] = (f32x4){0.f, 0.f, 0.f, 0.f};
    const int arow = (w * 16 + col16) * 256;

    auto COMP = [&](const unsigned short* SWb, const unsigned short* SOb) {
#pragma unroll
        for (int kkl = 0; kkl < 4; ++kkl) {
            int ko = (((kkl * 4 + quad) ^ c7) << 4);
            bf16x8 a = ldb8((const char*)SWb + arow + ko);
#pragma unroll
            for (int n = 0; n < 2; ++n) {
                bf16x8 b = ldb8((const char*)SOb + (n * 16 + col16) * 256 + ko);
                acc[n] = __builtin_amdgcn_mfma_f32_16x16x32_bf16(a, b, acc[n], 0, 0, 0);
            }
        }
    };

    STG(0, SW0, SO0);
    DRAIN_BAR();
    STG(1, SW1, SO1);  COMP(SW0, SO0);  DRAIN_BAR();
    STG(2, SW0, SO0);  COMP(SW1, SO1);  DRAIN_BAR();
    STG(3, SW1, SO1);  COMP(SW0, SO0);  DRAIN_BAR();
    COMP(SW1, SO1);

    // epilogue: D[o = w*16+quad*4+r][p = n*16+col16] -> per-wave LDS
    // transpose (pitch 36 f32, region in SW0 — not read by last COMP) ->
    // coalesced float4 stores.
    __syncthreads();
    float* otw = (float*)&SW0[0] + (size_t)w * (16 * 36);
#pragma unroll
    for (int n = 0; n < 2; ++n)
#pragma unroll
        for (int r = 0; r < 4; ++r)
            otw[(quad * 4 + r) * 36 + n * 16 + col16] = acc[n][r];
    int r2 = lane >> 2, csg = (lane & 3) * 8;
#pragma unroll
    for (int j = 0; j < 2; ++j) {
        float4 v = *(const float4*)&otw[r2 * 36 + csg + j * 4];
        *(float4*)&out[(size_t)(o0 + w * 16 + r2) * SPAT + p0 + csg + j * 4] = v;
    }
}

// ---------------------------------------------------------------------------
// Launch
// ---------------------------------------------------------------------------
extern "C" void kernel_launch(void* const* d_in, const int* in_sizes, int n_in,
                              void* d_out, int out_size, void* d_ws, size_t ws_size,
                              hipStream_t stream) {
    const float* x      = (const float*)d_in[0];
    const float* gamma  = (const float*)d_in[1];
    const float* mem_kv = (const float*)d_in[2];
    const float* w_qkv  = (const float*)d_in[3];
    const float* w_out  = (const float*)d_in[4];
    float* out = (float*)d_out;

    // workspace (bf16 unless noted): xb | wb | wob | qb | kb | vtb | obb | spb(f32)
    unsigned short* xb  = (unsigned short*)d_ws;                 // 4096*256
    unsigned short* wb  = xb + (size_t)SPAT * C_DIM;             // 1536*256
    unsigned short* wob = wb + (size_t)3 * HID * C_DIM;          // 256*512
    unsigned short* qb  = wob + (size_t)C_DIM * HID;             // 8*4096*64
    unsigned short* kb  = qb + (size_t)HEADS_N * SPAT * DHEAD;   // 8*4224*64
    unsigned short* vtb = kb + (size_t)HEADS_N * TTOKP * DHEAD;  // 8*64*4224
    unsigned short* obb = vtb + (size_t)HEADS_N * DHEAD * TTOKP; // 4096*512
    float* spb = (float*)(obb + (size_t)SPAT * HID);             // 4096

    prep_kernel<<<dim3(1088), 256, 0, stream>>>(x, gamma, mem_kv, w_qkv, w_out,
                                                xb, spb, wb, wob, kb, vtb);
    qkv_mfma<<<dim3(64, 24), 256, 0, stream>>>(wb, xb, spb, qb, kb, vtb);
    attn_mfma<<<dim3(512), 256, 0, stream>>>(qb, kb, vtb, obb);
    out_mfma<<<dim3(128, 4), 256, 0, stream>>>(wob, obb, out);
}